// Round 1
// baseline (219.863 us; speedup 1.0000x reference)
//
#include <hip/hip_runtime.h>
#include <hip/hip_bf16.h>
#include <stdint.h>

using bf16 = __hip_bfloat16;

typedef __bf16 bf16x8 __attribute__((ext_vector_type(8)));
typedef float  f32x4  __attribute__((ext_vector_type(4)));

constexpr int Bc = 4, Hh = 8, Dh = 128, S = 2048, Cn = 1024, O3 = 3072;
constexpr float SCALE = 0.08838834764831845f;  // 1/sqrt(128)

// async global->LDS, 16B per lane, wave-uniform LDS base + lane*16 scatter
#define GLDS16(gp, lp)                                               \
  __builtin_amdgcn_global_load_lds(                                  \
      (const __attribute__((address_space(1))) void*)(gp),           \
      (__attribute__((address_space(3))) void*)(lp), 16, 0, 0)

// ---------------------------------------------------------------------------
// BT-GEMM core (m97 structure): acc[m][n] += sum_k A[m][k] * B[n][k]
// 128x128 output tile, 256 threads = 4 waves, each wave a 64x64 quadrant
// (4x4 tiles of 16x16x32 MFMA). A,B row-major, contiguous in k.
// ---------------------------------------------------------------------------
__device__ __forceinline__ void gemm_bt_core(
    const bf16* __restrict__ Abase, int lda,
    const bf16* __restrict__ Bbase, int ldb,
    int kIters, f32x4 (&acc)[4][4])
{
  alignas(16) __shared__ bf16 As[128 * 32];
  alignas(16) __shared__ bf16 Bs[128 * 32];
  const int t    = threadIdx.x;
  const int lane = t & 63;
  const int quad = lane >> 4, r16 = lane & 15;
  const int wave = t >> 6;
  const int wm = (wave & 1) * 64, wn = (wave >> 1) * 64;
  const int lrow = lane >> 2;        // 0..15 within a 16-row chunk
  const int lk   = (lane & 3) * 8;   // k-offset (elems)

  const long aOff0 = (long)(wave * 32 + lrow) * lda + lk;
  const long aOff1 = aOff0 + 16l * lda;
  const long bOff0 = (long)(wave * 32 + lrow) * ldb + lk;
  const long bOff1 = bOff0 + 16l * ldb;
  bf16* aL0 = &As[(wave * 32) * 32];
  bf16* aL1 = &As[(wave * 32 + 16) * 32];
  bf16* bL0 = &Bs[(wave * 32) * 32];
  bf16* bL1 = &Bs[(wave * 32 + 16) * 32];

#pragma unroll
  for (int i = 0; i < 4; i++)
#pragma unroll
    for (int j = 0; j < 4; j++) acc[i][j] = {0.f, 0.f, 0.f, 0.f};

  for (int ks = 0; ks < kIters; ++ks) {
    const int k0 = ks * 32;
    __syncthreads();  // all waves done reading LDS from previous iter
    GLDS16(Abase + k0 + aOff0, aL0);
    GLDS16(Abase + k0 + aOff1, aL1);
    GLDS16(Bbase + k0 + bOff0, bL0);
    GLDS16(Bbase + k0 + bOff1, bL1);
    __syncthreads();  // drains vmcnt(0): DMA'd data visible to all waves
    bf16x8 af[4], bfr[4];
#pragma unroll
    for (int i = 0; i < 4; i++)
      af[i] = *(const bf16x8*)&As[(wm + i * 16 + r16) * 32 + quad * 8];
#pragma unroll
    for (int j = 0; j < 4; j++)
      bfr[j] = *(const bf16x8*)&Bs[(wn + j * 16 + r16) * 32 + quad * 8];
#pragma unroll
    for (int i = 0; i < 4; i++)
#pragma unroll
      for (int j = 0; j < 4; j++)
        acc[i][j] = __builtin_amdgcn_mfma_f32_16x16x32_bf16(af[i], bfr[j], acc[i][j], 0, 0, 0);
  }
}

__device__ __forceinline__ void store_bf16_tile(
    f32x4 (&acc)[4][4], bf16* __restrict__ Cp, int ldc)
{
  const int t = threadIdx.x;
  const int lane = t & 63;
  const int quad = lane >> 4, r16 = lane & 15;
  const int wave = t >> 6;
  const int wm = (wave & 1) * 64, wn = (wave >> 1) * 64;
#pragma unroll
  for (int i = 0; i < 4; i++)
#pragma unroll
    for (int j = 0; j < 4; j++)
#pragma unroll
      for (int r = 0; r < 4; r++) {
        const int row = wm + i * 16 + quad * 4 + r;
        const int col = wn + j * 16 + r16;
        Cp[(long)row * ldc + col] = __float2bfloat16(acc[i][j][r]);
      }
}

__device__ __forceinline__ void store_f32_tile(
    f32x4 (&acc)[4][4], float* __restrict__ Cp, int ldc)
{
  const int t = threadIdx.x;
  const int lane = t & 63;
  const int quad = lane >> 4, r16 = lane & 15;
  const int wave = t >> 6;
  const int wm = (wave & 1) * 64, wn = (wave >> 1) * 64;
#pragma unroll
  for (int i = 0; i < 4; i++)
#pragma unroll
    for (int j = 0; j < 4; j++)
#pragma unroll
      for (int r = 0; r < 4; r++) {
        const int row = wm + i * 16 + quad * 4 + r;
        const int col = wn + j * 16 + r16;
        Cp[(long)row * ldc + col] = acc[i][j][r];
      }
}

// ---- KV-part of W_qkv + W_out: f32 -> bf16, float4-vectorized, one dispatch.
// Q-part of W_qkv is NOT converted (only its transpose is needed, see below).
__global__ __launch_bounds__(256) void k_cvt_w(
    const float* __restrict__ Wkv, const float* __restrict__ Wout,
    bf16* __restrict__ WkvB, bf16* __restrict__ WoutB)
{
  const long v = (long)blockIdx.x * 256 + threadIdx.x;  // 786,432 vec4 total
  const bool isK = v < 524288;                          // 2048*1024/4
  const float4 f = isK ? ((const float4*)Wkv)[v] : ((const float4*)Wout)[v - 524288];
  bf16 tmp[4];
  tmp[0] = __float2bfloat16(f.x);
  tmp[1] = __float2bfloat16(f.y);
  tmp[2] = __float2bfloat16(f.z);
  tmp[3] = __float2bfloat16(f.w);
  ushort4 u = *(ushort4*)tmp;
  if (isK) ((ushort4*)WkvB)[v] = u;
  else     ((ushort4*)WoutB)[v - 524288] = u;
}

// ---- generic transpose+convert: f32 (R x C) -> bf16 (C x R) per z-slice ----
// out[c][r] = in[r][c]; grid = (C/32, R/32, Z)
__global__ __launch_bounds__(256) void k_transpose_cvt(
    const float* __restrict__ in, bf16* __restrict__ out, long inZ, long outZ,
    int inld, int outld)
{
  __shared__ bf16 tile[32][33];
  const float* ip = in + (long)blockIdx.z * inZ;
  bf16* op = out + (long)blockIdx.z * outZ;
  const int c0 = blockIdx.x * 32, r0 = blockIdx.y * 32;
  const int tx = threadIdx.x & 31, ty = threadIdx.x >> 5;  // 32 x 8
#pragma unroll
  for (int i = 0; i < 32; i += 8)
    tile[ty + i][tx] = __float2bfloat16(ip[(long)(r0 + ty + i) * inld + c0 + tx]);
  __syncthreads();
#pragma unroll
  for (int i = 0; i < 32; i += 8)
    op[(long)(c0 + ty + i) * outld + r0 + tx] = tile[tx][ty + i];
}

// ---- KV[b][o'][s] = sum_c Wkv[o'][c] * x[b][c][s]  (o',s layout) ----
// o' in [0,2048): rows 0..1023 = K (per-head e), 1024..2047 = V (per-head d)
__global__ __launch_bounds__(256) void k_gemm_kv(
    const bf16* __restrict__ WkvB, const bf16* __restrict__ xT, bf16* __restrict__ KV)
{
  const int m0 = blockIdx.x * 128, n0 = blockIdx.y * 128, b = blockIdx.z;
  f32x4 acc[4][4];
  gemm_bt_core(WkvB + (long)m0 * Cn, Cn,
               xT + (long)b * S * Cn + (long)n0 * Cn, Cn, Cn / 32, acc);
  store_bf16_tile(acc, KV + (long)b * 2048 * S + (long)m0 * S + n0, S);
}

// ---- MTpart[chunk][z][e][d] = K_h . V_h^T over a 256-wide s-chunk ----
__global__ __launch_bounds__(256) void k_gemm_mt(
    const bf16* __restrict__ KV, float* __restrict__ MTpart)
{
  const int chunk = blockIdx.x;               // 8 chunks of 256 along s
  const int z = blockIdx.y;                   // b*8 + h
  const int b = z >> 3, h = z & 7;
  const bf16* base = KV + (long)b * 2048 * S;
  const bf16* A  = base + (long)(h * Dh) * S + chunk * 256;           // K rows (e)
  const bf16* Bp = base + (long)(1024 + h * Dh) * S + chunk * 256;    // V rows (d)
  f32x4 acc[4][4];
  gemm_bt_core(A, S, Bp, S, 8, acc);
  store_f32_tile(acc, MTpart + ((long)chunk * 32 + z) * (Dh * Dh), Dh);
}

// ---- MbT[z][e][d] = bf16(SCALE * sum_chunk MTpart) ----
__global__ __launch_bounds__(256) void k_reduce_mt(
    const float* __restrict__ MTpart, bf16* __restrict__ MbT)
{
  const long i = (long)blockIdx.x * 256 + threadIdx.x;  // 524,288 total
  float s = 0.f;
#pragma unroll
  for (int c = 0; c < 8; c++) s += MTpart[(long)c * 32 * Dh * Dh + i];
  MbT[i] = __float2bfloat16(s * SCALE);
}

// ---- W2[b][o][h*128+e] = sum_d Wout[o][h*128+d] * MbT[b,h][e][d] ----
__global__ __launch_bounds__(256) void k_gemm_w2(
    const bf16* __restrict__ WoutB, const bf16* __restrict__ MbT, bf16* __restrict__ W2)
{
  const int m0 = blockIdx.x * 128;  // o tile
  const int h = blockIdx.y, b = blockIdx.z;
  const int z = b * 8 + h;
  f32x4 acc[4][4];
  gemm_bt_core(WoutB + (long)m0 * Cn + h * Dh, Cn,
               MbT + (long)z * Dh * Dh, Dh, 4, acc);
  store_bf16_tile(acc, W2 + (long)b * Cn * Cn + (long)m0 * Cn + h * Dh, Cn);
}

// ---- W3[b][o][c] = sum_u W2[b][o][u] * Wq[u][c]   (the new fold) ----
// B-operand is WqT[c][u] (row-major in u), so BT-core applies directly.
__global__ __launch_bounds__(256) void k_gemm_w3(
    const bf16* __restrict__ W2, const bf16* __restrict__ WqT, bf16* __restrict__ W3)
{
  const int m0 = blockIdx.x * 128, n0 = blockIdx.y * 128, b = blockIdx.z;
  f32x4 acc[4][4];
  gemm_bt_core(W2 + (long)b * Cn * Cn + (long)m0 * Cn, Cn,
               WqT + (long)n0 * Cn, Cn, Cn / 32, acc);
  store_bf16_tile(acc, W3 + (long)b * Cn * Cn + (long)m0 * Cn + n0, Cn);
}

// ---- out[b][o][s] = sum_c W3[b][o][c] * xT[b][s][c] -> f32 final ----
__global__ __launch_bounds__(256) void k_gemm_out(
    const bf16* __restrict__ W3, const bf16* __restrict__ xT, float* __restrict__ out)
{
  const int m0 = blockIdx.x * 128, n0 = blockIdx.y * 128, b = blockIdx.z;
  f32x4 acc[4][4];
  gemm_bt_core(W3 + (long)b * Cn * Cn + (long)m0 * Cn, Cn,
               xT + (long)b * S * Cn + (long)n0 * Cn, Cn, Cn / 32, acc);
  store_f32_tile(acc, out + (long)b * Cn * S + (long)m0 * S + n0, S);
}

extern "C" void kernel_launch(void* const* d_in, const int* in_sizes, int n_in,
                              void* d_out, int out_size, void* d_ws, size_t ws_size,
                              hipStream_t stream)
{
  const float* x    = (const float*)d_in[0];  // (4,1024,2048) f32
  const float* Wqkv = (const float*)d_in[1];  // (3072,1024)   f32
  const float* Wout = (const float*)d_in[2];  // (1024,1024)   f32
  float* out = (float*)d_out;                 // (4,1024,2048) f32

  char* ws = (char*)d_ws;
  bf16*  KV     = (bf16*)ws;                     // 33,554,432 B
  bf16*  xT     = (bf16*)(ws + 33554432);        // 16,777,216 B (live till end)
  float* MTpart = (float*)(ws + 50331648);       // 16,777,216 B (dead after reduce)
  bf16*  W3     = (bf16*)(ws + 50331648);        //  8,388,608 B (aliases MTpart)
  bf16*  WkvB   = (bf16*)(ws + 67108864);        //  4,194,304 B
  bf16*  WoutB  = (bf16*)(ws + 71303168);        //  2,097,152 B
  bf16*  WqT    = (bf16*)(ws + 73400320);        //  2,097,152 B
  bf16*  MbT    = (bf16*)(ws + 75497472);        //  1,048,576 B
  bf16*  W2     = (bf16*)(ws + 76546048);        //  8,388,608 B (end 84,934,656)

  // KV-part of W_qkv + W_out: f32 -> bf16 (one dispatch, float4)
  k_cvt_w<<<dim3(3072), 256, 0, stream>>>(Wqkv + (long)Cn * Cn, Wout, WkvB, WoutB);
  // xT[b] = bf16(x[b]^T): (1024 x 2048) -> (2048 x 1024)
  k_transpose_cvt<<<dim3(64, 32, 4), 256, 0, stream>>>(
      x, xT, (long)1024 * 2048, (long)2048 * 1024, 2048, 1024);
  // WqT = bf16(Wq^T): (1024 x 1024) -> (1024 x 1024)
  k_transpose_cvt<<<dim3(32, 32, 1), 256, 0, stream>>>(
      Wqkv, WqT, 0, 0, 1024, 1024);
  // K,V in (o,s) layout for the MT GEMM
  k_gemm_kv<<<dim3(16, 16, 4), 256, 0, stream>>>(WkvB, xT, KV);
  // MT partials: K_h . V_h^T over 8 s-chunks (no atomics)
  k_gemm_mt<<<dim3(8, 32), 256, 0, stream>>>(KV, MTpart);
  // MbT = bf16(SCALE * sum of partials)
  k_reduce_mt<<<dim3(2048), 256, 0, stream>>>(MTpart, MbT);
  // W2[b] = Wout . blockdiag(scale*M): folded output weights
  k_gemm_w2<<<dim3(8, 8, 4), 256, 0, stream>>>(WoutB, MbT, W2);
  // W3[b] = W2[b] . Wq: fold Q projection into the output weights
  k_gemm_w3<<<dim3(8, 8, 4), 256, 0, stream>>>(W2, WqT, W3);
  // out[b] = W3[b] . x[b]  (f32 output; QT GEMM eliminated)
  k_gemm_out<<<dim3(8, 16, 4), 256, 0, stream>>>(W3, xT, out);
}

// Round 2
// 213.292 us; speedup vs baseline: 1.0308x; 1.0308x over previous
//
#include <hip/hip_runtime.h>
#include <hip/hip_bf16.h>
#include <stdint.h>

using bf16 = __hip_bfloat16;

typedef __bf16 bf16x8 __attribute__((ext_vector_type(8)));
typedef float  f32x4  __attribute__((ext_vector_type(4)));

constexpr int Bc = 4, Hh = 8, Dh = 128, S = 2048, Cn = 1024, O3 = 3072;
constexpr float SCALE = 0.08838834764831845f;  // 1/sqrt(128)

// async global->LDS, 16B per lane, wave-uniform LDS base + lane*16 scatter
#define GLDS16(gp, lp)                                               \
  __builtin_amdgcn_global_load_lds(                                  \
      (const __attribute__((address_space(1))) void*)(gp),           \
      (__attribute__((address_space(3))) void*)(lp), 16, 0, 0)

#define WAITVM(N) asm volatile("s_waitcnt vmcnt(" #N ")" ::: "memory")
#define BAR()                                  \
  do {                                         \
    asm volatile("" ::: "memory");             \
    __builtin_amdgcn_s_barrier();              \
    asm volatile("" ::: "memory");             \
  } while (0)

// ---------------------------------------------------------------------------
// BT-GEMM core (m97 structure): acc[m][n] += sum_k A[m][k] * B[n][k]
// 128x128 output tile, 256 threads = 4 waves, each wave a 64x64 quadrant
// (4x4 tiles of 16x16x32 MFMA). A,B row-major, contiguous in k.
// ---------------------------------------------------------------------------
__device__ __forceinline__ void gemm_bt_core(
    const bf16* __restrict__ Abase, int lda,
    const bf16* __restrict__ Bbase, int ldb,
    int kIters, f32x4 (&acc)[4][4])
{
  alignas(16) __shared__ bf16 As[128 * 32];
  alignas(16) __shared__ bf16 Bs[128 * 32];
  const int t    = threadIdx.x;
  const int lane = t & 63;
  const int quad = lane >> 4, r16 = lane & 15;
  const int wave = t >> 6;
  const int wm = (wave & 1) * 64, wn = (wave >> 1) * 64;
  const int lrow = lane >> 2;        // 0..15 within a 16-row chunk
  const int lk   = (lane & 3) * 8;   // k-offset (elems)

  const long aOff0 = (long)(wave * 32 + lrow) * lda + lk;
  const long aOff1 = aOff0 + 16l * lda;
  const long bOff0 = (long)(wave * 32 + lrow) * ldb + lk;
  const long bOff1 = bOff0 + 16l * ldb;
  bf16* aL0 = &As[(wave * 32) * 32];
  bf16* aL1 = &As[(wave * 32 + 16) * 32];
  bf16* bL0 = &Bs[(wave * 32) * 32];
  bf16* bL1 = &Bs[(wave * 32 + 16) * 32];

#pragma unroll
  for (int i = 0; i < 4; i++)
#pragma unroll
    for (int j = 0; j < 4; j++) acc[i][j] = {0.f, 0.f, 0.f, 0.f};

  for (int ks = 0; ks < kIters; ++ks) {
    const int k0 = ks * 32;
    __syncthreads();  // all waves done reading LDS from previous iter
    GLDS16(Abase + k0 + aOff0, aL0);
    GLDS16(Abase + k0 + aOff1, aL1);
    GLDS16(Bbase + k0 + bOff0, bL0);
    GLDS16(Bbase + k0 + bOff1, bL1);
    __syncthreads();  // drains vmcnt(0): DMA'd data visible to all waves
    bf16x8 af[4], bfr[4];
#pragma unroll
    for (int i = 0; i < 4; i++)
      af[i] = *(const bf16x8*)&As[(wm + i * 16 + r16) * 32 + quad * 8];
#pragma unroll
    for (int j = 0; j < 4; j++)
      bfr[j] = *(const bf16x8*)&Bs[(wn + j * 16 + r16) * 32 + quad * 8];
#pragma unroll
    for (int i = 0; i < 4; i++)
#pragma unroll
      for (int j = 0; j < 4; j++)
        acc[i][j] = __builtin_amdgcn_mfma_f32_16x16x32_bf16(af[i], bfr[j], acc[i][j], 0, 0, 0);
  }
}

__device__ __forceinline__ void store_bf16_tile(
    f32x4 (&acc)[4][4], bf16* __restrict__ Cp, int ldc)
{
  const int t = threadIdx.x;
  const int lane = t & 63;
  const int quad = lane >> 4, r16 = lane & 15;
  const int wave = t >> 6;
  const int wm = (wave & 1) * 64, wn = (wave >> 1) * 64;
#pragma unroll
  for (int i = 0; i < 4; i++)
#pragma unroll
    for (int j = 0; j < 4; j++)
#pragma unroll
      for (int r = 0; r < 4; r++) {
        const int row = wm + i * 16 + quad * 4 + r;
        const int col = wn + j * 16 + r16;
        Cp[(long)row * ldc + col] = __float2bfloat16(acc[i][j][r]);
      }
}

__device__ __forceinline__ void store_f32_tile(
    f32x4 (&acc)[4][4], float* __restrict__ Cp, int ldc)
{
  const int t = threadIdx.x;
  const int lane = t & 63;
  const int quad = lane >> 4, r16 = lane & 15;
  const int wave = t >> 6;
  const int wm = (wave & 1) * 64, wn = (wave >> 1) * 64;
#pragma unroll
  for (int i = 0; i < 4; i++)
#pragma unroll
    for (int j = 0; j < 4; j++)
#pragma unroll
      for (int r = 0; r < 4; r++) {
        const int row = wm + i * 16 + quad * 4 + r;
        const int col = wn + j * 16 + r16;
        Cp[(long)row * ldc + col] = acc[i][j][r];
      }
}

// ---------------------------------------------------------------------------
// 256x256-tile 8-phase-style GEMM for KV = Wkv . x  (BT form, all batches).
//   M=2048 (o'), N=8192 (b*2048+s), K=1024.  256 blocks of 512 threads.
//   BK=32, 4 LDS buffers (128 KiB), counted vmcnt(8) (2 tiles in flight),
//   XOR-swizzled LDS (2-way = free), setprio around MFMA, XCD swizzle.
// Pipeline safety: tile t's phases stage tile t+3 into buf[(t+3)&3] =
// buf[(t-1)&3], whose last ds_reads completed before tile t-1's trailing
// barrier (lgkmcnt enforced by MFMA data-dep). vmcnt(8) at tile t retires
// the 4 oldest in-flight loads = all of tile t+1 (FIFO), so buf[(t+1)&3]
// is landed before the following barrier. Tail: waits tighten 8 -> 4 -> 0.
// ---------------------------------------------------------------------------
__global__ __launch_bounds__(512, 2) void k_gemm_kv8(
    const bf16* __restrict__ WkvB, const bf16* __restrict__ xT, bf16* __restrict__ KV)
{
  constexpr int NT = Cn / 32;  // 32 K-tiles
  alignas(16) __shared__ bf16 smem[4 * 16384];  // 4 x (A 8192 + B 8192) = 128 KiB

  // XCD-aware bijective swizzle: 256 blocks, each XCD owns one m-row
  // -> its 512 KB A-panel stays L2-resident.
  const int orig = blockIdx.x;
  const int swz  = (orig & 7) * 32 + (orig >> 3);
  const int mt = swz >> 5;             // 0..7  (o' tile)
  const int nt = swz & 31;             // 0..31 (global s tile; 8 per batch)
  const int m0 = mt * 256;

  const int tid  = threadIdx.x;
  const int lane = tid & 63;
  const int w    = tid >> 6;           // wave 0..7
  const int quad = lane >> 4, r16 = lane & 15;
  const int wm = (w >> 2) * 128;       // wave_m in {0,1}
  const int wn = (w & 3) * 64;         // wave_n in {0..3}

  // --- staging geometry: one GLDS stmt/wave covers 16 rows x 64B ---
  const int srow = w * 16 + (lane >> 2);             // row within 128-row half
  const int cx   = (lane & 3) ^ ((lane >> 3) & 3);   // inverse-swizzled k-chunk
  const bf16* Ag = WkvB + (long)(m0 + srow) * Cn + cx * 8;
  const bf16* Bg = xT + (long)((long)nt * 256 + srow) * Cn + cx * 8;
  const int ldsW = w * 512;  // per-wave 1 KiB slice (in bf16 elems)

#define KV8_STAGE_A(tt)                                                   \
  do {                                                                    \
    const int k0_ = (tt) * 32, bb_ = ((tt) & 3) * 16384;                  \
    GLDS16(Ag + k0_,            &smem[bb_ + ldsW]);                       \
    GLDS16(Ag + 128l * Cn + k0_, &smem[bb_ + 4096 + ldsW]);               \
  } while (0)
#define KV8_STAGE_B(tt)                                                   \
  do {                                                                    \
    const int k0_ = (tt) * 32, bb_ = ((tt) & 3) * 16384;                  \
    GLDS16(Bg + k0_,            &smem[bb_ + 8192 + ldsW]);                \
    GLDS16(Bg + 128l * Cn + k0_, &smem[bb_ + 8192 + 4096 + ldsW]);        \
  } while (0)

  // swizzled chunk offset for fragment reads (elems); 2-way bank = free
  const int sc8 = (quad ^ ((r16 >> 1) & 3)) * 8;

  f32x4 acc[8][4];
#pragma unroll
  for (int m = 0; m < 8; m++)
#pragma unroll
    for (int n = 0; n < 4; n++) acc[m][n] = {0.f, 0.f, 0.f, 0.f};

  // prologue: stage tiles 0,1,2 (12 loads/wave); wait oldest 4 => tile 0 landed
  KV8_STAGE_A(0); KV8_STAGE_B(0);
  KV8_STAGE_A(1); KV8_STAGE_B(1);
  KV8_STAGE_A(2); KV8_STAGE_B(2);
  WAITVM(8);
  BAR();

#pragma unroll 2
  for (int tt = 0; tt < NT; ++tt) {
    const bf16* Ab = &smem[(tt & 3) * 16384];
    const bf16* Bb = Ab + 8192;
    bf16x8 af[4], bfr[4];

    // ---- phase 1: m 0..3 x n 0..3 ----
#pragma unroll
    for (int n = 0; n < 4; n++)
      bfr[n] = *(const bf16x8*)&Bb[(wn + n * 16 + r16) * 32 + sc8];
#pragma unroll
    for (int m = 0; m < 4; m++)
      af[m] = *(const bf16x8*)&Ab[(wm + m * 16 + r16) * 32 + sc8];
    if (tt + 3 < NT) KV8_STAGE_A(tt + 3);
    BAR();
    __builtin_amdgcn_s_setprio(1);
#pragma unroll
    for (int m = 0; m < 4; m++)
#pragma unroll
      for (int n = 0; n < 4; n++)
        acc[m][n] = __builtin_amdgcn_mfma_f32_16x16x32_bf16(af[m], bfr[n], acc[m][n], 0, 0, 0);
    __builtin_amdgcn_s_setprio(0);
    BAR();

    // ---- phase 2: m 4..7 x n 0..3 (reuse bfr) ----
#pragma unroll
    for (int m = 0; m < 4; m++)
      af[m] = *(const bf16x8*)&Ab[(wm + (m + 4) * 16 + r16) * 32 + sc8];
    if (tt + 3 < NT) KV8_STAGE_B(tt + 3);
    if (tt <= NT - 4)      { WAITVM(8); }
    else if (tt == NT - 3) { WAITVM(4); }
    else if (tt == NT - 2) { WAITVM(0); }
    BAR();
    __builtin_amdgcn_s_setprio(1);
#pragma unroll
    for (int m = 0; m < 4; m++)
#pragma unroll
      for (int n = 0; n < 4; n++)
        acc[m + 4][n] = __builtin_amdgcn_mfma_f32_16x16x32_bf16(af[m], bfr[n], acc[m + 4][n], 0, 0, 0);
    __builtin_amdgcn_s_setprio(0);
    BAR();
  }

  // epilogue: per-wave 128x64 sub-tile -> KV[b][o'][s]
  bf16* Cp = KV + (long)(nt >> 3) * 2048 * S + (long)m0 * S + (nt & 7) * 256;
#pragma unroll
  for (int m = 0; m < 8; m++)
#pragma unroll
    for (int n = 0; n < 4; n++)
#pragma unroll
      for (int r = 0; r < 4; r++) {
        const int row = wm + m * 16 + quad * 4 + r;
        const int col = wn + n * 16 + r16;
        Cp[(long)row * S + col] = __float2bfloat16(acc[m][n][r]);
      }
#undef KV8_STAGE_A
#undef KV8_STAGE_B
}

// ---- KV-part of W_qkv + W_out: f32 -> bf16, float4-vectorized, one dispatch.
// Q-part of W_qkv is NOT converted (only its transpose is needed, see below).
__global__ __launch_bounds__(256) void k_cvt_w(
    const float* __restrict__ Wkv, const float* __restrict__ Wout,
    bf16* __restrict__ WkvB, bf16* __restrict__ WoutB)
{
  const long v = (long)blockIdx.x * 256 + threadIdx.x;  // 786,432 vec4 total
  const bool isK = v < 524288;                          // 2048*1024/4
  const float4 f = isK ? ((const float4*)Wkv)[v] : ((const float4*)Wout)[v - 524288];
  bf16 tmp[4];
  tmp[0] = __float2bfloat16(f.x);
  tmp[1] = __float2bfloat16(f.y);
  tmp[2] = __float2bfloat16(f.z);
  tmp[3] = __float2bfloat16(f.w);
  ushort4 u = *(ushort4*)tmp;
  if (isK) ((ushort4*)WkvB)[v] = u;
  else     ((ushort4*)WoutB)[v - 524288] = u;
}

// ---- generic transpose+convert: f32 (R x C) -> bf16 (C x R) per z-slice ----
// out[c][r] = in[r][c]; grid = (C/32, R/32, Z)
__global__ __launch_bounds__(256) void k_transpose_cvt(
    const float* __restrict__ in, bf16* __restrict__ out, long inZ, long outZ,
    int inld, int outld)
{
  __shared__ bf16 tile[32][33];
  const float* ip = in + (long)blockIdx.z * inZ;
  bf16* op = out + (long)blockIdx.z * outZ;
  const int c0 = blockIdx.x * 32, r0 = blockIdx.y * 32;
  const int tx = threadIdx.x & 31, ty = threadIdx.x >> 5;  // 32 x 8
#pragma unroll
  for (int i = 0; i < 32; i += 8)
    tile[ty + i][tx] = __float2bfloat16(ip[(long)(r0 + ty + i) * inld + c0 + tx]);
  __syncthreads();
#pragma unroll
  for (int i = 0; i < 32; i += 8)
    op[(long)(c0 + ty + i) * outld + r0 + tx] = tile[tx][ty + i];
}

// ---- MTpart[chunk][z][e][d] = K_h . V_h^T over a 256-wide s-chunk ----
__global__ __launch_bounds__(256) void k_gemm_mt(
    const bf16* __restrict__ KV, float* __restrict__ MTpart)
{
  const int chunk = blockIdx.x;               // 8 chunks of 256 along s
  const int z = blockIdx.y;                   // b*8 + h
  const int b = z >> 3, h = z & 7;
  const bf16* base = KV + (long)b * 2048 * S;
  const bf16* A  = base + (long)(h * Dh) * S + chunk * 256;           // K rows (e)
  const bf16* Bp = base + (long)(1024 + h * Dh) * S + chunk * 256;    // V rows (d)
  f32x4 acc[4][4];
  gemm_bt_core(A, S, Bp, S, 8, acc);
  store_f32_tile(acc, MTpart + ((long)chunk * 32 + z) * (Dh * Dh), Dh);
}

// ---- MbT[z][e][d] = bf16(SCALE * sum_chunk MTpart) ----
__global__ __launch_bounds__(256) void k_reduce_mt(
    const float* __restrict__ MTpart, bf16* __restrict__ MbT)
{
  const long i = (long)blockIdx.x * 256 + threadIdx.x;  // 524,288 total
  float s = 0.f;
#pragma unroll
  for (int c = 0; c < 8; c++) s += MTpart[(long)c * 32 * Dh * Dh + i];
  MbT[i] = __float2bfloat16(s * SCALE);
}

// ---- W2[b][o][h*128+e] = sum_d Wout[o][h*128+d] * MbT[b,h][e][d] ----
__global__ __launch_bounds__(256) void k_gemm_w2(
    const bf16* __restrict__ WoutB, const bf16* __restrict__ MbT, bf16* __restrict__ W2)
{
  const int m0 = blockIdx.x * 128;  // o tile
  const int h = blockIdx.y, b = blockIdx.z;
  const int z = b * 8 + h;
  f32x4 acc[4][4];
  gemm_bt_core(WoutB + (long)m0 * Cn + h * Dh, Cn,
               MbT + (long)z * Dh * Dh, Dh, 4, acc);
  store_bf16_tile(acc, W2 + (long)b * Cn * Cn + (long)m0 * Cn + h * Dh, Cn);
}

// ---- W3[b][o][c] = sum_u W2[b][o][u] * Wq[u][c]   (folded Q projection) ----
__global__ __launch_bounds__(256) void k_gemm_w3(
    const bf16* __restrict__ W2, const bf16* __restrict__ WqT, bf16* __restrict__ W3)
{
  const int m0 = blockIdx.x * 128, n0 = blockIdx.y * 128, b = blockIdx.z;
  f32x4 acc[4][4];
  gemm_bt_core(W2 + (long)b * Cn * Cn + (long)m0 * Cn, Cn,
               WqT + (long)n0 * Cn, Cn, Cn / 32, acc);
  store_bf16_tile(acc, W3 + (long)b * Cn * Cn + (long)m0 * Cn + n0, Cn);
}

// ---- out[b][o][s] = sum_c W3[b][o][c] * xT[b][s][c] -> f32 final ----
__global__ __launch_bounds__(256) void k_gemm_out(
    const bf16* __restrict__ W3, const bf16* __restrict__ xT, float* __restrict__ out)
{
  const int m0 = blockIdx.x * 128, n0 = blockIdx.y * 128, b = blockIdx.z;
  f32x4 acc[4][4];
  gemm_bt_core(W3 + (long)b * Cn * Cn + (long)m0 * Cn, Cn,
               xT + (long)b * S * Cn + (long)n0 * Cn, Cn, Cn / 32, acc);
  store_f32_tile(acc, out + (long)b * Cn * S + (long)m0 * S + n0, S);
}

extern "C" void kernel_launch(void* const* d_in, const int* in_sizes, int n_in,
                              void* d_out, int out_size, void* d_ws, size_t ws_size,
                              hipStream_t stream)
{
  const float* x    = (const float*)d_in[0];  // (4,1024,2048) f32
  const float* Wqkv = (const float*)d_in[1];  // (3072,1024)   f32
  const float* Wout = (const float*)d_in[2];  // (1024,1024)   f32
  float* out = (float*)d_out;                 // (4,1024,2048) f32

  char* ws = (char*)d_ws;
  bf16*  KV     = (bf16*)ws;                     // 33,554,432 B
  bf16*  xT     = (bf16*)(ws + 33554432);        // 16,777,216 B (live till end)
  float* MTpart = (float*)(ws + 50331648);       // 16,777,216 B (dead after reduce)
  bf16*  W3     = (bf16*)(ws + 50331648);        //  8,388,608 B (aliases MTpart)
  bf16*  WkvB   = (bf16*)(ws + 67108864);        //  4,194,304 B
  bf16*  WoutB  = (bf16*)(ws + 71303168);        //  2,097,152 B
  bf16*  WqT    = (bf16*)(ws + 73400320);        //  2,097,152 B
  bf16*  MbT    = (bf16*)(ws + 75497472);        //  1,048,576 B
  bf16*  W2     = (bf16*)(ws + 76546048);        //  8,388,608 B (end 84,934,656)

  // KV-part of W_qkv + W_out: f32 -> bf16 (one dispatch, float4)
  k_cvt_w<<<dim3(3072), 256, 0, stream>>>(Wqkv + (long)Cn * Cn, Wout, WkvB, WoutB);
  // xT[b] = bf16(x[b]^T): (1024 x 2048) -> (2048 x 1024)
  k_transpose_cvt<<<dim3(64, 32, 4), 256, 0, stream>>>(
      x, xT, (long)1024 * 2048, (long)2048 * 1024, 2048, 1024);
  // WqT = bf16(Wq^T): (1024 x 1024) -> (1024 x 1024)
  k_transpose_cvt<<<dim3(32, 32, 1), 256, 0, stream>>>(
      Wqkv, WqT, 0, 0, 1024, 1024);
  // K,V in (o,s) layout, 256^2-tile pipelined GEMM (all batches, one dispatch)
  k_gemm_kv8<<<dim3(256), 512, 0, stream>>>(WkvB, xT, KV);
  // MT partials: K_h . V_h^T over 8 s-chunks (no atomics)
  k_gemm_mt<<<dim3(8, 32), 256, 0, stream>>>(KV, MTpart);
  // MbT = bf16(SCALE * sum of partials)
  k_reduce_mt<<<dim3(2048), 256, 0, stream>>>(MTpart, MbT);
  // W2[b] = Wout . blockdiag(scale*M): folded output weights
  k_gemm_w2<<<dim3(8, 8, 4), 256, 0, stream>>>(WoutB, MbT, W2);
  // W3[b] = W2[b] . Wq: fold Q projection into the output weights
  k_gemm_w3<<<dim3(8, 8, 4), 256, 0, stream>>>(W2, WqT, W3);
  // out[b] = W3[b] . x[b]  (f32 output)
  k_gemm_out<<<dim3(8, 16, 4), 256, 0, stream>>>(W3, xT, out);
}

// Round 3
// 202.894 us; speedup vs baseline: 1.0836x; 1.0512x over previous
//
#include <hip/hip_runtime.h>
#include <hip/hip_bf16.h>
#include <stdint.h>

using bf16 = __hip_bfloat16;

typedef __bf16 bf16x8 __attribute__((ext_vector_type(8)));
typedef float  f32x4  __attribute__((ext_vector_type(4)));

constexpr int Bc = 4, Hh = 8, Dh = 128, S = 2048, Cn = 1024, O3 = 3072;
constexpr float SCALE = 0.08838834764831845f;  // 1/sqrt(128)

// async global->LDS, 16B per lane, wave-uniform LDS base + lane*16 scatter
#define GLDS16(gp, lp)                                               \
  __builtin_amdgcn_global_load_lds(                                  \
      (const __attribute__((address_space(1))) void*)(gp),           \
      (__attribute__((address_space(3))) void*)(lp), 16, 0, 0)

#define WAITVM(N) asm volatile("s_waitcnt vmcnt(" #N ")" ::: "memory")
#define BAR()                                  \
  do {                                         \
    asm volatile("" ::: "memory");             \
    __builtin_amdgcn_s_barrier();              \
    asm volatile("" ::: "memory");             \
  } while (0)

// ---------------------------------------------------------------------------
// BT-GEMM core (m97 structure): acc[m][n] += sum_k A[m][k] * B[n][k]
// 128x128 output tile, 256 threads = 4 waves, each wave a 64x64 quadrant.
// Used by the small GEMMs (mt, w2, w3) where grid/shape don't fit the
// pipelined 8-wave core.
// ---------------------------------------------------------------------------
__device__ __forceinline__ void gemm_bt_core(
    const bf16* __restrict__ Abase, int lda,
    const bf16* __restrict__ Bbase, int ldb,
    int kIters, f32x4 (&acc)[4][4])
{
  alignas(16) __shared__ bf16 As[128 * 32];
  alignas(16) __shared__ bf16 Bs[128 * 32];
  const int t    = threadIdx.x;
  const int lane = t & 63;
  const int quad = lane >> 4, r16 = lane & 15;
  const int wave = t >> 6;
  const int wm = (wave & 1) * 64, wn = (wave >> 1) * 64;
  const int lrow = lane >> 2;        // 0..15 within a 16-row chunk
  const int lk   = (lane & 3) * 8;   // k-offset (elems)

  const long aOff0 = (long)(wave * 32 + lrow) * lda + lk;
  const long aOff1 = aOff0 + 16l * lda;
  const long bOff0 = (long)(wave * 32 + lrow) * ldb + lk;
  const long bOff1 = bOff0 + 16l * ldb;
  bf16* aL0 = &As[(wave * 32) * 32];
  bf16* aL1 = &As[(wave * 32 + 16) * 32];
  bf16* bL0 = &Bs[(wave * 32) * 32];
  bf16* bL1 = &Bs[(wave * 32 + 16) * 32];

#pragma unroll
  for (int i = 0; i < 4; i++)
#pragma unroll
    for (int j = 0; j < 4; j++) acc[i][j] = {0.f, 0.f, 0.f, 0.f};

  for (int ks = 0; ks < kIters; ++ks) {
    const int k0 = ks * 32;
    __syncthreads();
    GLDS16(Abase + k0 + aOff0, aL0);
    GLDS16(Abase + k0 + aOff1, aL1);
    GLDS16(Bbase + k0 + bOff0, bL0);
    GLDS16(Bbase + k0 + bOff1, bL1);
    __syncthreads();
    bf16x8 af[4], bfr[4];
#pragma unroll
    for (int i = 0; i < 4; i++)
      af[i] = *(const bf16x8*)&As[(wm + i * 16 + r16) * 32 + quad * 8];
#pragma unroll
    for (int j = 0; j < 4; j++)
      bfr[j] = *(const bf16x8*)&Bs[(wn + j * 16 + r16) * 32 + quad * 8];
#pragma unroll
    for (int i = 0; i < 4; i++)
#pragma unroll
      for (int j = 0; j < 4; j++)
        acc[i][j] = __builtin_amdgcn_mfma_f32_16x16x32_bf16(af[i], bfr[j], acc[i][j], 0, 0, 0);
  }
}

__device__ __forceinline__ void store_bf16_tile(
    f32x4 (&acc)[4][4], bf16* __restrict__ Cp, int ldc)
{
  const int t = threadIdx.x;
  const int lane = t & 63;
  const int quad = lane >> 4, r16 = lane & 15;
  const int wave = t >> 6;
  const int wm = (wave & 1) * 64, wn = (wave >> 1) * 64;
#pragma unroll
  for (int i = 0; i < 4; i++)
#pragma unroll
    for (int j = 0; j < 4; j++)
#pragma unroll
      for (int r = 0; r < 4; r++) {
        const int row = wm + i * 16 + quad * 4 + r;
        const int col = wn + j * 16 + r16;
        Cp[(long)row * ldc + col] = __float2bfloat16(acc[i][j][r]);
      }
}

__device__ __forceinline__ void store_f32_tile(
    f32x4 (&acc)[4][4], float* __restrict__ Cp, int ldc)
{
  const int t = threadIdx.x;
  const int lane = t & 63;
  const int quad = lane >> 4, r16 = lane & 15;
  const int wave = t >> 6;
  const int wm = (wave & 1) * 64, wn = (wave >> 1) * 64;
#pragma unroll
  for (int i = 0; i < 4; i++)
#pragma unroll
    for (int j = 0; j < 4; j++)
#pragma unroll
      for (int r = 0; r < 4; r++) {
        const int row = wm + i * 16 + quad * 4 + r;
        const int col = wn + j * 16 + r16;
        Cp[(long)row * ldc + col] = acc[i][j][r];
      }
}

// ---------------------------------------------------------------------------
// 256x256 pipelined GEMM for KV = Wkv . x  (BT form, all batches).
//   M=2048, N=8192, K=1024. 256 blocks x 512 threads, 4 LDS buffers (128 KiB).
// v3: ds_read/MFMA OVERLAP. Per K-tile, 2 barriers:
//   [BAR A] stage(t+3) | ds_read(p2 A-frags) | MFMA p1 (regs preloaded)
//   vmcnt(8) [BAR B]   MFMA p2 | ds_read(tile t+1 p1 frags)
// Safety: reads of buf t-1 all precede BAR A(t) (p2 reads in window t-1,
// look-ahead reads end of window t-2). Cross-wave RAW on buf t+1: every
// wave's vmcnt(8) retires exactly tile t+1's 4 loads (FIFO), then BAR B
// orders the look-ahead reads. Tail waits 8 -> 4 -> 0 as in v2 (proven).
// ---------------------------------------------------------------------------
__global__ __launch_bounds__(512, 2) void k_gemm_kv8(
    const bf16* __restrict__ WkvB, const bf16* __restrict__ xT, bf16* __restrict__ KV)
{
  constexpr int NT = Cn / 32;  // 32 K-tiles
  alignas(16) __shared__ bf16 smem[4 * 16384];  // 4 x (A 8192 + B 8192)

  const int orig = blockIdx.x;
  const int swz  = (orig & 7) * 32 + (orig >> 3);
  const int mt = swz >> 5;             // 0..7  (o' tile)
  const int nt = swz & 31;             // 0..31 (global s tile; 8 per batch)
  const int m0 = mt * 256;

  const int tid  = threadIdx.x;
  const int lane = tid & 63;
  const int w    = tid >> 6;
  const int quad = lane >> 4, r16 = lane & 15;
  const int wm = (w >> 2) * 128;
  const int wn = (w & 3) * 64;

  const int srow = w * 16 + (lane >> 2);
  const int cx   = (lane & 3) ^ ((lane >> 3) & 3);   // inverse-swizzled k-chunk
  const bf16* Ag = WkvB + (long)(m0 + srow) * Cn + cx * 8;
  const bf16* Bg = xT + (long)((long)nt * 256 + srow) * Cn + cx * 8;
  const int ldsW = w * 512;

#define KV8_STAGE_A(tt)                                                   \
  do {                                                                    \
    const int k0_ = (tt) * 32, bb_ = ((tt) & 3) * 16384;                  \
    GLDS16(Ag + k0_,             &smem[bb_ + ldsW]);                      \
    GLDS16(Ag + 128l * Cn + k0_, &smem[bb_ + 4096 + ldsW]);               \
  } while (0)
#define KV8_STAGE_B(tt)                                                   \
  do {                                                                    \
    const int k0_ = (tt) * 32, bb_ = ((tt) & 3) * 16384;                  \
    GLDS16(Bg + k0_,             &smem[bb_ + 8192 + ldsW]);               \
    GLDS16(Bg + 128l * Cn + k0_, &smem[bb_ + 8192 + 4096 + ldsW]);        \
  } while (0)

  const int sc8 = (quad ^ ((r16 >> 1) & 3)) * 8;  // swizzled chunk, 2-way=free

  f32x4 acc[8][4];
#pragma unroll
  for (int m = 0; m < 8; m++)
#pragma unroll
    for (int n = 0; n < 4; n++) acc[m][n] = {0.f, 0.f, 0.f, 0.f};

  // prologue: stage tiles 0,1,2 (12 loads/wave); retire tile 0's 4
  KV8_STAGE_A(0); KV8_STAGE_B(0);
  KV8_STAGE_A(1); KV8_STAGE_B(1);
  KV8_STAGE_A(2); KV8_STAGE_B(2);
  WAITVM(8);
  BAR();

  bf16x8 af0[4], bfr0[4], af1[4];
  {  // preload tile 0 phase-1 fragments
    const bf16* Ab = &smem[0];
    const bf16* Bb = Ab + 8192;
#pragma unroll
    for (int n = 0; n < 4; n++)
      bfr0[n] = *(const bf16x8*)&Bb[(wn + n * 16 + r16) * 32 + sc8];
#pragma unroll
    for (int m = 0; m < 4; m++)
      af0[m] = *(const bf16x8*)&Ab[(wm + m * 16 + r16) * 32 + sc8];
  }

#pragma unroll 4
  for (int tt = 0; tt < NT; ++tt) {
    const bf16* Ab = &smem[(tt & 3) * 16384];

    BAR();  // BAR A: buf (t-1)&3 fully read -> safe to stage t+3 into it
    if (tt + 3 < NT) { KV8_STAGE_A(tt + 3); KV8_STAGE_B(tt + 3); }
#pragma unroll
    for (int m = 0; m < 4; m++)
      af1[m] = *(const bf16x8*)&Ab[(wm + (m + 4) * 16 + r16) * 32 + sc8];
    __builtin_amdgcn_s_setprio(1);
#pragma unroll
    for (int m = 0; m < 4; m++)
#pragma unroll
      for (int n = 0; n < 4; n++)
        acc[m][n] = __builtin_amdgcn_mfma_f32_16x16x32_bf16(af0[m], bfr0[n], acc[m][n], 0, 0, 0);
    __builtin_amdgcn_s_setprio(0);

    if (tt <= NT - 4)      { WAITVM(8); }
    else if (tt == NT - 3) { WAITVM(4); }
    else if (tt == NT - 2) { WAITVM(0); }
    BAR();  // BAR B: every wave's vmcnt retired tile t+1 -> buf t+1 readable

    __builtin_amdgcn_s_setprio(1);
#pragma unroll
    for (int m = 0; m < 4; m++)
#pragma unroll
      for (int n = 0; n < 4; n++)
        acc[m + 4][n] = __builtin_amdgcn_mfma_f32_16x16x32_bf16(af1[m], bfr0[n], acc[m + 4][n], 0, 0, 0);
    __builtin_amdgcn_s_setprio(0);

    if (tt + 1 < NT) {  // look-ahead: tile t+1 phase-1 fragments
      const bf16* Ab2 = &smem[((tt + 1) & 3) * 16384];
      const bf16* Bb2 = Ab2 + 8192;
#pragma unroll
      for (int n = 0; n < 4; n++)
        bfr0[n] = *(const bf16x8*)&Bb2[(wn + n * 16 + r16) * 32 + sc8];
#pragma unroll
      for (int m = 0; m < 4; m++)
        af0[m] = *(const bf16x8*)&Ab2[(wm + m * 16 + r16) * 32 + sc8];
    }
  }

  // epilogue: per-wave 128x64 sub-tile -> KV[b][o'][s]
  bf16* Cp = KV + (long)(nt >> 3) * 2048 * S + (long)m0 * S + (nt & 7) * 256;
#pragma unroll
  for (int m = 0; m < 8; m++)
#pragma unroll
    for (int n = 0; n < 4; n++)
#pragma unroll
      for (int r = 0; r < 4; r++) {
        const int row = wm + m * 16 + quad * 4 + r;
        const int col = wn + n * 16 + r16;
        Cp[(long)row * S + col] = __float2bfloat16(acc[m][n][r]);
      }
#undef KV8_STAGE_A
#undef KV8_STAGE_B
}

// ---------------------------------------------------------------------------
// 128x256 pipelined GEMM for out = W3[b] . x[b]  (same overlap schedule).
//   Per batch M=1024, N=2048, K=1024. Grid 256 (8 o x 8 s x 4 b), 512 thr.
//   LDS: 4 buffers x (A 4096 + B 8192) elems = 96 KiB. 3 loads/tile/wave
//   -> counted vmcnt(6), tails 3 -> 0.
// ---------------------------------------------------------------------------
__global__ __launch_bounds__(512, 2) void k_gemm_out8(
    const bf16* __restrict__ W3, const bf16* __restrict__ xT, float* __restrict__ out)
{
  constexpr int NT = Cn / 32;  // 32
  alignas(16) __shared__ bf16 smem[4 * 12288];  // 96 KiB

  const int orig = blockIdx.x;
  const int swz  = (orig & 7) * 32 + (orig >> 3);
  const int b  = swz >> 6;
  const int mt = (swz >> 3) & 7;
  const int nt = swz & 7;
  const int m0 = mt * 128, n0 = nt * 256;

  const int tid  = threadIdx.x;
  const int lane = tid & 63;
  const int w    = tid >> 6;
  const int quad = lane >> 4, r16 = lane & 15;
  const int wm = (w >> 2) * 64;   // 2 m-groups of 64
  const int wn = (w & 3) * 64;    // 4 n-groups of 64 (covers 256)

  const int srow = w * 16 + (lane >> 2);           // 0..127
  const int cx   = (lane & 3) ^ ((lane >> 3) & 3);
  const bf16* Ag = W3 + (long)b * Cn * Cn + (long)(m0 + srow) * Cn + cx * 8;
  const bf16* Bg = xT + (long)b * S * Cn + (long)(n0 + srow) * Cn + cx * 8;
  const int ldsW = w * 512;

#define OUT_STAGE(tt)                                                     \
  do {                                                                    \
    const int k0_ = (tt) * 32, bb_ = ((tt) & 3) * 12288;                  \
    GLDS16(Ag + k0_,             &smem[bb_ + ldsW]);                      \
    GLDS16(Bg + k0_,             &smem[bb_ + 4096 + ldsW]);               \
    GLDS16(Bg + 128l * Cn + k0_, &smem[bb_ + 8192 + ldsW]);               \
  } while (0)

  const int sc8 = (quad ^ ((r16 >> 1) & 3)) * 8;

  f32x4 acc[4][4];
#pragma unroll
  for (int m = 0; m < 4; m++)
#pragma unroll
    for (int n = 0; n < 4; n++) acc[m][n] = {0.f, 0.f, 0.f, 0.f};

  // prologue: 9 loads/wave in flight; retire tile 0's 3
  OUT_STAGE(0); OUT_STAGE(1); OUT_STAGE(2);
  WAITVM(6);
  BAR();

  bf16x8 af0[2], bfr0[4], af1[2];
  {
    const bf16* Ab = &smem[0];
    const bf16* Bb = Ab + 4096;
#pragma unroll
    for (int n = 0; n < 4; n++)
      bfr0[n] = *(const bf16x8*)&Bb[(wn + n * 16 + r16) * 32 + sc8];
#pragma unroll
    for (int m = 0; m < 2; m++)
      af0[m] = *(const bf16x8*)&Ab[(wm + m * 16 + r16) * 32 + sc8];
  }

#pragma unroll 4
  for (int tt = 0; tt < NT; ++tt) {
    const bf16* Ab = &smem[(tt & 3) * 12288];

    BAR();  // BAR A
    if (tt + 3 < NT) OUT_STAGE(tt + 3);
#pragma unroll
    for (int m = 0; m < 2; m++)
      af1[m] = *(const bf16x8*)&Ab[(wm + (m + 2) * 16 + r16) * 32 + sc8];
    __builtin_amdgcn_s_setprio(1);
#pragma unroll
    for (int m = 0; m < 2; m++)
#pragma unroll
      for (int n = 0; n < 4; n++)
        acc[m][n] = __builtin_amdgcn_mfma_f32_16x16x32_bf16(af0[m], bfr0[n], acc[m][n], 0, 0, 0);
    __builtin_amdgcn_s_setprio(0);

    if (tt <= NT - 4)      { WAITVM(6); }
    else if (tt == NT - 3) { WAITVM(3); }
    else if (tt == NT - 2) { WAITVM(0); }
    BAR();  // BAR B

    __builtin_amdgcn_s_setprio(1);
#pragma unroll
    for (int m = 0; m < 2; m++)
#pragma unroll
      for (int n = 0; n < 4; n++)
        acc[m + 2][n] = __builtin_amdgcn_mfma_f32_16x16x32_bf16(af1[m], bfr0[n], acc[m + 2][n], 0, 0, 0);
    __builtin_amdgcn_s_setprio(0);

    if (tt + 1 < NT) {
      const bf16* Ab2 = &smem[((tt + 1) & 3) * 12288];
      const bf16* Bb2 = Ab2 + 4096;
#pragma unroll
      for (int n = 0; n < 4; n++)
        bfr0[n] = *(const bf16x8*)&Bb2[(wn + n * 16 + r16) * 32 + sc8];
#pragma unroll
      for (int m = 0; m < 2; m++)
        af0[m] = *(const bf16x8*)&Ab2[(wm + m * 16 + r16) * 32 + sc8];
    }
  }

  // epilogue: per-wave 64x64 sub-tile -> out[b][o][s], f32 coalesced
  float* Cp = out + (long)b * Cn * S + (long)m0 * S + n0;
#pragma unroll
  for (int m = 0; m < 4; m++)
#pragma unroll
    for (int n = 0; n < 4; n++)
#pragma unroll
      for (int r = 0; r < 4; r++) {
        const int row = wm + m * 16 + quad * 4 + r;
        const int col = wn + n * 16 + r16;
        Cp[(long)row * S + col] = acc[m][n][r];
      }
#undef OUT_STAGE
}

// ---- KV-part of W_qkv + W_out: f32 -> bf16, float4-vectorized ----
__global__ __launch_bounds__(256) void k_cvt_w(
    const float* __restrict__ Wkv, const float* __restrict__ Wout,
    bf16* __restrict__ WkvB, bf16* __restrict__ WoutB)
{
  const long v = (long)blockIdx.x * 256 + threadIdx.x;  // 786,432 vec4 total
  const bool isK = v < 524288;                          // 2048*1024/4
  const float4 f = isK ? ((const float4*)Wkv)[v] : ((const float4*)Wout)[v - 524288];
  bf16 tmp[4];
  tmp[0] = __float2bfloat16(f.x);
  tmp[1] = __float2bfloat16(f.y);
  tmp[2] = __float2bfloat16(f.z);
  tmp[3] = __float2bfloat16(f.w);
  ushort4 u = *(ushort4*)tmp;
  if (isK) ((ushort4*)WkvB)[v] = u;
  else     ((ushort4*)WoutB)[v - 524288] = u;
}

// ---- generic transpose+convert: f32 (R x C) -> bf16 (C x R) per z-slice ----
__global__ __launch_bounds__(256) void k_transpose_cvt(
    const float* __restrict__ in, bf16* __restrict__ out, long inZ, long outZ,
    int inld, int outld)
{
  __shared__ bf16 tile[32][33];
  const float* ip = in + (long)blockIdx.z * inZ;
  bf16* op = out + (long)blockIdx.z * outZ;
  const int c0 = blockIdx.x * 32, r0 = blockIdx.y * 32;
  const int tx = threadIdx.x & 31, ty = threadIdx.x >> 5;  // 32 x 8
#pragma unroll
  for (int i = 0; i < 32; i += 8)
    tile[ty + i][tx] = __float2bfloat16(ip[(long)(r0 + ty + i) * inld + c0 + tx]);
  __syncthreads();
#pragma unroll
  for (int i = 0; i < 32; i += 8)
    op[(long)(c0 + ty + i) * outld + r0 + tx] = tile[tx][ty + i];
}

// ---- MTpart[chunk][z][e][d] = K_h . V_h^T over a 256-wide s-chunk ----
__global__ __launch_bounds__(256) void k_gemm_mt(
    const bf16* __restrict__ KV, float* __restrict__ MTpart)
{
  const int chunk = blockIdx.x;               // 8 chunks of 256 along s
  const int z = blockIdx.y;                   // b*8 + h
  const int b = z >> 3, h = z & 7;
  const bf16* base = KV + (long)b * 2048 * S;
  const bf16* A  = base + (long)(h * Dh) * S + chunk * 256;
  const bf16* Bp = base + (long)(1024 + h * Dh) * S + chunk * 256;
  f32x4 acc[4][4];
  gemm_bt_core(A, S, Bp, S, 8, acc);
  store_f32_tile(acc, MTpart + ((long)chunk * 32 + z) * (Dh * Dh), Dh);
}

// ---- MbT[z][e][d] = bf16(SCALE * sum_chunk MTpart) ----
__global__ __launch_bounds__(256) void k_reduce_mt(
    const float* __restrict__ MTpart, bf16* __restrict__ MbT)
{
  const long i = (long)blockIdx.x * 256 + threadIdx.x;  // 524,288 total
  float s = 0.f;
#pragma unroll
  for (int c = 0; c < 8; c++) s += MTpart[(long)c * 32 * Dh * Dh + i];
  MbT[i] = __float2bfloat16(s * SCALE);
}

// ---- W2[b][o][h*128+e] = sum_d Wout[o][h*128+d] * MbT[b,h][e][d] ----
__global__ __launch_bounds__(256) void k_gemm_w2(
    const bf16* __restrict__ WoutB, const bf16* __restrict__ MbT, bf16* __restrict__ W2)
{
  const int m0 = blockIdx.x * 128;
  const int h = blockIdx.y, b = blockIdx.z;
  const int z = b * 8 + h;
  f32x4 acc[4][4];
  gemm_bt_core(WoutB + (long)m0 * Cn + h * Dh, Cn,
               MbT + (long)z * Dh * Dh, Dh, 4, acc);
  store_bf16_tile(acc, W2 + (long)b * Cn * Cn + (long)m0 * Cn + h * Dh, Cn);
}

// ---- W3[b][o][c] = sum_u W2[b][o][u] * Wq[u][c]   (folded Q projection) ----
__global__ __launch_bounds__(256) void k_gemm_w3(
    const bf16* __restrict__ W2, const bf16* __restrict__ WqT, bf16* __restrict__ W3)
{
  const int m0 = blockIdx.x * 128, n0 = blockIdx.y * 128, b = blockIdx.z;
  f32x4 acc[4][4];
  gemm_bt_core(W2 + (long)b * Cn * Cn + (long)m0 * Cn, Cn,
               WqT + (long)n0 * Cn, Cn, Cn / 32, acc);
  store_bf16_tile(acc, W3 + (long)b * Cn * Cn + (long)m0 * Cn + n0, Cn);
}

extern "C" void kernel_launch(void* const* d_in, const int* in_sizes, int n_in,
                              void* d_out, int out_size, void* d_ws, size_t ws_size,
                              hipStream_t stream)
{
  const float* x    = (const float*)d_in[0];  // (4,1024,2048) f32
  const float* Wqkv = (const float*)d_in[1];  // (3072,1024)   f32
  const float* Wout = (const float*)d_in[2];  // (1024,1024)   f32
  float* out = (float*)d_out;                 // (4,1024,2048) f32

  char* ws = (char*)d_ws;
  bf16*  KV     = (bf16*)ws;                     // 33,554,432 B
  bf16*  xT     = (bf16*)(ws + 33554432);        // 16,777,216 B (live till end)
  float* MTpart = (float*)(ws + 50331648);       // 16,777,216 B (dead after reduce)
  bf16*  W3     = (bf16*)(ws + 50331648);        //  8,388,608 B (aliases MTpart)
  bf16*  WkvB   = (bf16*)(ws + 67108864);        //  4,194,304 B
  bf16*  WoutB  = (bf16*)(ws + 71303168);        //  2,097,152 B
  bf16*  WqT    = (bf16*)(ws + 73400320);        //  2,097,152 B
  bf16*  MbT    = (bf16*)(ws + 75497472);        //  1,048,576 B
  bf16*  W2     = (bf16*)(ws + 76546048);        //  8,388,608 B (end 84,934,656)

  k_cvt_w<<<dim3(3072), 256, 0, stream>>>(Wqkv + (long)Cn * Cn, Wout, WkvB, WoutB);
  k_transpose_cvt<<<dim3(64, 32, 4), 256, 0, stream>>>(
      x, xT, (long)1024 * 2048, (long)2048 * 1024, 2048, 1024);
  k_transpose_cvt<<<dim3(32, 32, 1), 256, 0, stream>>>(
      Wqkv, WqT, 0, 0, 1024, 1024);
  k_gemm_kv8<<<dim3(256), 512, 0, stream>>>(WkvB, xT, KV);
  k_gemm_mt<<<dim3(8, 32), 256, 0, stream>>>(KV, MTpart);
  k_reduce_mt<<<dim3(2048), 256, 0, stream>>>(MTpart, MbT);
  k_gemm_w2<<<dim3(8, 8, 4), 256, 0, stream>>>(WoutB, MbT, W2);
  k_gemm_w3<<<dim3(8, 8, 4), 256, 0, stream>>>(W2, WqT, W3);
  k_gemm_out8<<<dim3(256), 512, 0, stream>>>(W3, xT, out);
}

// Round 4
// 197.838 us; speedup vs baseline: 1.1113x; 1.0256x over previous
//
#include <hip/hip_runtime.h>
#include <hip/hip_bf16.h>
#include <stdint.h>

using bf16 = __hip_bfloat16;

typedef __bf16 bf16x8 __attribute__((ext_vector_type(8)));
typedef float  f32x4  __attribute__((ext_vector_type(4)));

constexpr int Bc = 4, Hh = 8, Dh = 128, S = 2048, Cn = 1024, O3 = 3072;
constexpr float SCALE = 0.08838834764831845f;  // 1/sqrt(128)

// async global->LDS, 16B per lane, wave-uniform LDS base + lane*16 scatter
#define GLDS16(gp, lp)                                               \
  __builtin_amdgcn_global_load_lds(                                  \
      (const __attribute__((address_space(1))) void*)(gp),           \
      (__attribute__((address_space(3))) void*)(lp), 16, 0, 0)

#define WAITVM(N) asm volatile("s_waitcnt vmcnt(" #N ")" ::: "memory")
#define BAR()                                  \
  do {                                         \
    asm volatile("" ::: "memory");             \
    __builtin_amdgcn_s_barrier();              \
    asm volatile("" ::: "memory");             \
  } while (0)

// ---------------------------------------------------------------------------
// BT-GEMM core (m97 structure): acc[m][n] += sum_k A[m][k] * B[n][k]
// 128x128 output tile, 256 threads = 4 waves. Used by the small GEMMs
// (mt, w2) which run at >=1 block/CU with short K.
// ---------------------------------------------------------------------------
__device__ __forceinline__ void gemm_bt_core(
    const bf16* __restrict__ Abase, int lda,
    const bf16* __restrict__ Bbase, int ldb,
    int kIters, f32x4 (&acc)[4][4])
{
  alignas(16) __shared__ bf16 As[128 * 32];
  alignas(16) __shared__ bf16 Bs[128 * 32];
  const int t    = threadIdx.x;
  const int lane = t & 63;
  const int quad = lane >> 4, r16 = lane & 15;
  const int wave = t >> 6;
  const int wm = (wave & 1) * 64, wn = (wave >> 1) * 64;
  const int lrow = lane >> 2;        // 0..15 within a 16-row chunk
  const int lk   = (lane & 3) * 8;   // k-offset (elems)

  const long aOff0 = (long)(wave * 32 + lrow) * lda + lk;
  const long aOff1 = aOff0 + 16l * lda;
  const long bOff0 = (long)(wave * 32 + lrow) * ldb + lk;
  const long bOff1 = bOff0 + 16l * ldb;
  bf16* aL0 = &As[(wave * 32) * 32];
  bf16* aL1 = &As[(wave * 32 + 16) * 32];
  bf16* bL0 = &Bs[(wave * 32) * 32];
  bf16* bL1 = &Bs[(wave * 32 + 16) * 32];

#pragma unroll
  for (int i = 0; i < 4; i++)
#pragma unroll
    for (int j = 0; j < 4; j++) acc[i][j] = {0.f, 0.f, 0.f, 0.f};

  for (int ks = 0; ks < kIters; ++ks) {
    const int k0 = ks * 32;
    __syncthreads();
    GLDS16(Abase + k0 + aOff0, aL0);
    GLDS16(Abase + k0 + aOff1, aL1);
    GLDS16(Bbase + k0 + bOff0, bL0);
    GLDS16(Bbase + k0 + bOff1, bL1);
    __syncthreads();
    bf16x8 af[4], bfr[4];
#pragma unroll
    for (int i = 0; i < 4; i++)
      af[i] = *(const bf16x8*)&As[(wm + i * 16 + r16) * 32 + quad * 8];
#pragma unroll
    for (int j = 0; j < 4; j++)
      bfr[j] = *(const bf16x8*)&Bs[(wn + j * 16 + r16) * 32 + quad * 8];
#pragma unroll
    for (int i = 0; i < 4; i++)
#pragma unroll
      for (int j = 0; j < 4; j++)
        acc[i][j] = __builtin_amdgcn_mfma_f32_16x16x32_bf16(af[i], bfr[j], acc[i][j], 0, 0, 0);
  }
}

__device__ __forceinline__ void store_bf16_tile(
    f32x4 (&acc)[4][4], bf16* __restrict__ Cp, int ldc)
{
  const int t = threadIdx.x;
  const int lane = t & 63;
  const int quad = lane >> 4, r16 = lane & 15;
  const int wave = t >> 6;
  const int wm = (wave & 1) * 64, wn = (wave >> 1) * 64;
#pragma unroll
  for (int i = 0; i < 4; i++)
#pragma unroll
    for (int j = 0; j < 4; j++)
#pragma unroll
      for (int r = 0; r < 4; r++) {
        const int row = wm + i * 16 + quad * 4 + r;
        const int col = wn + j * 16 + r16;
        Cp[(long)row * ldc + col] = __float2bfloat16(acc[i][j][r]);
      }
}

__device__ __forceinline__ void store_f32_tile(
    f32x4 (&acc)[4][4], float* __restrict__ Cp, int ldc)
{
  const int t = threadIdx.x;
  const int lane = t & 63;
  const int quad = lane >> 4, r16 = lane & 15;
  const int wave = t >> 6;
  const int wm = (wave & 1) * 64, wn = (wave >> 1) * 64;
#pragma unroll
  for (int i = 0; i < 4; i++)
#pragma unroll
    for (int j = 0; j < 4; j++)
#pragma unroll
      for (int r = 0; r < 4; r++) {
        const int row = wm + i * 16 + quad * 4 + r;
        const int col = wn + j * 16 + r16;
        Cp[(long)row * ldc + col] = acc[i][j][r];
      }
}

// ---------------------------------------------------------------------------
// 256x256 pipelined GEMM for KV = Wkv . x  (BT form, all batches).
//   M=2048, N=8192, K=1024. 256 blocks x 512 threads, 4 LDS buffers (128 KiB).
// Per K-tile, 2 barriers with ds_read/MFMA overlap (proven round 3):
//   [BAR A] stage(t+3) | ds_read(p2 A-frags) | MFMA p1 (regs preloaded)
//   vmcnt(8) [BAR B]   MFMA p2 | ds_read(tile t+1 p1 frags)
// XCD grouping (round 4): XCD = orig&7 owns nt in {4x..4x+3} x all 8 mt ->
// B-panels fetched once per XCD (2 MB) instead of all 32 (16 MB); A (4 MB
// total) re-fetched per XCD is cheap. Cuts L2-fetch ~138 -> ~48 MB.
// ---------------------------------------------------------------------------
__global__ __launch_bounds__(512, 2) void k_gemm_kv8(
    const bf16* __restrict__ WkvB, const bf16* __restrict__ xT, bf16* __restrict__ KV)
{
  constexpr int NT = Cn / 32;  // 32 K-tiles
  alignas(16) __shared__ bf16 smem[4 * 16384];  // 4 x (A 8192 + B 8192)

  const int orig = blockIdx.x;
  const int mt = orig >> 5;                               // 0..7  (o' tile)
  const int nt = ((orig & 7) << 2) | ((orig >> 3) & 3);   // 0..31 (s tile)
  const int m0 = mt * 256;

  const int tid  = threadIdx.x;
  const int lane = tid & 63;
  const int w    = tid >> 6;
  const int quad = lane >> 4, r16 = lane & 15;
  const int wm = (w >> 2) * 128;
  const int wn = (w & 3) * 64;

  const int srow = w * 16 + (lane >> 2);
  const int cx   = (lane & 3) ^ ((lane >> 3) & 3);   // inverse-swizzled k-chunk
  const bf16* Ag = WkvB + (long)(m0 + srow) * Cn + cx * 8;
  const bf16* Bg = xT + (long)((long)nt * 256 + srow) * Cn + cx * 8;
  const int ldsW = w * 512;

#define KV8_STAGE_A(tt)                                                   \
  do {                                                                    \
    const int k0_ = (tt) * 32, bb_ = ((tt) & 3) * 16384;                  \
    GLDS16(Ag + k0_,             &smem[bb_ + ldsW]);                      \
    GLDS16(Ag + 128l * Cn + k0_, &smem[bb_ + 4096 + ldsW]);               \
  } while (0)
#define KV8_STAGE_B(tt)                                                   \
  do {                                                                    \
    const int k0_ = (tt) * 32, bb_ = ((tt) & 3) * 16384;                  \
    GLDS16(Bg + k0_,             &smem[bb_ + 8192 + ldsW]);               \
    GLDS16(Bg + 128l * Cn + k0_, &smem[bb_ + 8192 + 4096 + ldsW]);        \
  } while (0)

  const int sc8 = (quad ^ ((r16 >> 1) & 3)) * 8;  // swizzled chunk, 2-way=free

  f32x4 acc[8][4];
#pragma unroll
  for (int m = 0; m < 8; m++)
#pragma unroll
    for (int n = 0; n < 4; n++) acc[m][n] = {0.f, 0.f, 0.f, 0.f};

  // prologue: stage tiles 0,1,2 (12 loads/wave); retire tile 0's 4
  KV8_STAGE_A(0); KV8_STAGE_B(0);
  KV8_STAGE_A(1); KV8_STAGE_B(1);
  KV8_STAGE_A(2); KV8_STAGE_B(2);
  WAITVM(8);
  BAR();

  bf16x8 af0[4], bfr0[4], af1[4];
  {  // preload tile 0 phase-1 fragments
    const bf16* Ab = &smem[0];
    const bf16* Bb = Ab + 8192;
#pragma unroll
    for (int n = 0; n < 4; n++)
      bfr0[n] = *(const bf16x8*)&Bb[(wn + n * 16 + r16) * 32 + sc8];
#pragma unroll
    for (int m = 0; m < 4; m++)
      af0[m] = *(const bf16x8*)&Ab[(wm + m * 16 + r16) * 32 + sc8];
  }

#pragma unroll 4
  for (int tt = 0; tt < NT; ++tt) {
    const bf16* Ab = &smem[(tt & 3) * 16384];

    BAR();  // BAR A: buf (t-1)&3 fully read -> safe to stage t+3 into it
    if (tt + 3 < NT) { KV8_STAGE_A(tt + 3); KV8_STAGE_B(tt + 3); }
#pragma unroll
    for (int m = 0; m < 4; m++)
      af1[m] = *(const bf16x8*)&Ab[(wm + (m + 4) * 16 + r16) * 32 + sc8];
    __builtin_amdgcn_s_setprio(1);
#pragma unroll
    for (int m = 0; m < 4; m++)
#pragma unroll
      for (int n = 0; n < 4; n++)
        acc[m][n] = __builtin_amdgcn_mfma_f32_16x16x32_bf16(af0[m], bfr0[n], acc[m][n], 0, 0, 0);
    __builtin_amdgcn_s_setprio(0);

    if (tt <= NT - 4)      { WAITVM(8); }
    else if (tt == NT - 3) { WAITVM(4); }
    else if (tt == NT - 2) { WAITVM(0); }
    BAR();  // BAR B: every wave's vmcnt retired tile t+1 -> buf t+1 readable

    __builtin_amdgcn_s_setprio(1);
#pragma unroll
    for (int m = 0; m < 4; m++)
#pragma unroll
      for (int n = 0; n < 4; n++)
        acc[m + 4][n] = __builtin_amdgcn_mfma_f32_16x16x32_bf16(af1[m], bfr0[n], acc[m + 4][n], 0, 0, 0);
    __builtin_amdgcn_s_setprio(0);

    if (tt + 1 < NT) {  // look-ahead: tile t+1 phase-1 fragments
      const bf16* Ab2 = &smem[((tt + 1) & 3) * 16384];
      const bf16* Bb2 = Ab2 + 8192;
#pragma unroll
      for (int n = 0; n < 4; n++)
        bfr0[n] = *(const bf16x8*)&Bb2[(wn + n * 16 + r16) * 32 + sc8];
#pragma unroll
      for (int m = 0; m < 4; m++)
        af0[m] = *(const bf16x8*)&Ab2[(wm + m * 16 + r16) * 32 + sc8];
    }
  }

  // epilogue: per-wave 128x64 sub-tile -> KV[b][o'][s]
  bf16* Cp = KV + (long)(nt >> 3) * 2048 * S + (long)m0 * S + (nt & 7) * 256;
#pragma unroll
  for (int m = 0; m < 8; m++)
#pragma unroll
    for (int n = 0; n < 4; n++)
#pragma unroll
      for (int r = 0; r < 4; r++) {
        const int row = wm + m * 16 + quad * 4 + r;
        const int col = wn + n * 16 + r16;
        Cp[(long)row * S + col] = __float2bfloat16(acc[m][n][r]);
      }
#undef KV8_STAGE_A
#undef KV8_STAGE_B
}

// ---------------------------------------------------------------------------
// 128x256 pipelined GEMM (overlap schedule): out = W2[b] . Q[b] -> f32.
//   Per batch M=1024, N=2048, K=1024. Grid 256 (8 o x 8 s x 4 b), 512 thr.
//   LDS: 4 buffers x (A 4096 + B 8192) elems = 96 KiB. 3 loads/tile/wave
//   -> counted vmcnt(6), tails 3 -> 0.
// ---------------------------------------------------------------------------
__global__ __launch_bounds__(512, 2) void k_gemm_out8(
    const bf16* __restrict__ W2, const bf16* __restrict__ QT, float* __restrict__ out)
{
  constexpr int NT = Cn / 32;  // 32
  alignas(16) __shared__ bf16 smem[4 * 12288];  // 96 KiB

  const int orig = blockIdx.x;
  const int swz  = (orig & 7) * 32 + (orig >> 3);
  const int b  = swz >> 6;
  const int mt = (swz >> 3) & 7;
  const int nt = swz & 7;
  const int m0 = mt * 128, n0 = nt * 256;

  const int tid  = threadIdx.x;
  const int lane = tid & 63;
  const int w    = tid >> 6;
  const int quad = lane >> 4, r16 = lane & 15;
  const int wm = (w >> 2) * 64;   // 2 m-groups of 64
  const int wn = (w & 3) * 64;    // 4 n-groups of 64 (covers 256)

  const int srow = w * 16 + (lane >> 2);           // 0..127
  const int cx   = (lane & 3) ^ ((lane >> 3) & 3);
  const bf16* Ag = W2 + (long)b * Cn * Cn + (long)(m0 + srow) * Cn + cx * 8;
  const bf16* Bg = QT + (long)b * S * Cn + (long)(n0 + srow) * Cn + cx * 8;
  const int ldsW = w * 512;

#define OUT_STAGE(tt)                                                     \
  do {                                                                    \
    const int k0_ = (tt) * 32, bb_ = ((tt) & 3) * 12288;                  \
    GLDS16(Ag + k0_,             &smem[bb_ + ldsW]);                      \
    GLDS16(Bg + k0_,             &smem[bb_ + 4096 + ldsW]);               \
    GLDS16(Bg + 128l * Cn + k0_, &smem[bb_ + 8192 + ldsW]);               \
  } while (0)

  const int sc8 = (quad ^ ((r16 >> 1) & 3)) * 8;

  f32x4 acc[4][4];
#pragma unroll
  for (int m = 0; m < 4; m++)
#pragma unroll
    for (int n = 0; n < 4; n++) acc[m][n] = {0.f, 0.f, 0.f, 0.f};

  OUT_STAGE(0); OUT_STAGE(1); OUT_STAGE(2);
  WAITVM(6);
  BAR();

  bf16x8 af0[2], bfr0[4], af1[2];
  {
    const bf16* Ab = &smem[0];
    const bf16* Bb = Ab + 4096;
#pragma unroll
    for (int n = 0; n < 4; n++)
      bfr0[n] = *(const bf16x8*)&Bb[(wn + n * 16 + r16) * 32 + sc8];
#pragma unroll
    for (int m = 0; m < 2; m++)
      af0[m] = *(const bf16x8*)&Ab[(wm + m * 16 + r16) * 32 + sc8];
  }

#pragma unroll 4
  for (int tt = 0; tt < NT; ++tt) {
    const bf16* Ab = &smem[(tt & 3) * 12288];

    BAR();  // BAR A
    if (tt + 3 < NT) OUT_STAGE(tt + 3);
#pragma unroll
    for (int m = 0; m < 2; m++)
      af1[m] = *(const bf16x8*)&Ab[(wm + (m + 2) * 16 + r16) * 32 + sc8];
    __builtin_amdgcn_s_setprio(1);
#pragma unroll
    for (int m = 0; m < 2; m++)
#pragma unroll
      for (int n = 0; n < 4; n++)
        acc[m][n] = __builtin_amdgcn_mfma_f32_16x16x32_bf16(af0[m], bfr0[n], acc[m][n], 0, 0, 0);
    __builtin_amdgcn_s_setprio(0);

    if (tt <= NT - 4)      { WAITVM(6); }
    else if (tt == NT - 3) { WAITVM(3); }
    else if (tt == NT - 2) { WAITVM(0); }
    BAR();  // BAR B

    __builtin_amdgcn_s_setprio(1);
#pragma unroll
    for (int m = 0; m < 2; m++)
#pragma unroll
      for (int n = 0; n < 4; n++)
        acc[m + 2][n] = __builtin_amdgcn_mfma_f32_16x16x32_bf16(af1[m], bfr0[n], acc[m + 2][n], 0, 0, 0);
    __builtin_amdgcn_s_setprio(0);

    if (tt + 1 < NT) {
      const bf16* Ab2 = &smem[((tt + 1) & 3) * 12288];
      const bf16* Bb2 = Ab2 + 4096;
#pragma unroll
      for (int n = 0; n < 4; n++)
        bfr0[n] = *(const bf16x8*)&Bb2[(wn + n * 16 + r16) * 32 + sc8];
#pragma unroll
      for (int m = 0; m < 2; m++)
        af0[m] = *(const bf16x8*)&Ab2[(wm + m * 16 + r16) * 32 + sc8];
    }
  }

  float* Cp = out + (long)b * Cn * S + (long)m0 * S + n0;
#pragma unroll
  for (int m = 0; m < 4; m++)
#pragma unroll
    for (int n = 0; n < 4; n++)
#pragma unroll
      for (int r = 0; r < 4; r++) {
        const int row = wm + m * 16 + quad * 4 + r;
        const int col = wn + n * 16 + r16;
        Cp[(long)row * S + col] = acc[m][n][r];
      }
#undef OUT_STAGE
}

// ---------------------------------------------------------------------------
// 128x256 pipelined GEMM: QT[b][s][u] = sum_c xT[b][s][c] * Wq[u][c] (bf16).
//   Per batch M=2048 (s), N=1024 (u), K=1024. Grid 256 (4b x 16 mt x 4 nt).
//   Same overlap schedule as k_gemm_out8. XCD = orig&7 -> nt fixed per XCD
//   (B-panel 512 KB L2-resident, read by 32 blocks).
// ---------------------------------------------------------------------------
__global__ __launch_bounds__(512, 2) void k_gemm_qt8(
    const bf16* __restrict__ xT, const bf16* __restrict__ WqB, bf16* __restrict__ QT)
{
  constexpr int NT = Cn / 32;  // 32
  alignas(16) __shared__ bf16 smem[4 * 12288];  // 96 KiB

  const int orig = blockIdx.x;
  const int b  = orig >> 6;          // 0..3
  const int mt = (orig >> 2) & 15;   // 0..15 (s tile of 128)
  const int nt = orig & 3;           // 0..3  (u tile of 256)
  const int m0 = mt * 128, n0 = nt * 256;

  const int tid  = threadIdx.x;
  const int lane = tid & 63;
  const int w    = tid >> 6;
  const int quad = lane >> 4, r16 = lane & 15;
  const int wm = (w >> 2) * 64;
  const int wn = (w & 3) * 64;

  const int srow = w * 16 + (lane >> 2);
  const int cx   = (lane & 3) ^ ((lane >> 3) & 3);
  const bf16* Ag = xT + (long)b * S * Cn + (long)(m0 + srow) * Cn + cx * 8;
  const bf16* Bg = WqB + (long)(n0 + srow) * Cn + cx * 8;
  const int ldsW = w * 512;

#define QT_STAGE(tt)                                                      \
  do {                                                                    \
    const int k0_ = (tt) * 32, bb_ = ((tt) & 3) * 12288;                  \
    GLDS16(Ag + k0_,             &smem[bb_ + ldsW]);                      \
    GLDS16(Bg + k0_,             &smem[bb_ + 4096 + ldsW]);               \
    GLDS16(Bg + 128l * Cn + k0_, &smem[bb_ + 8192 + ldsW]);               \
  } while (0)

  const int sc8 = (quad ^ ((r16 >> 1) & 3)) * 8;

  f32x4 acc[4][4];
#pragma unroll
  for (int m = 0; m < 4; m++)
#pragma unroll
    for (int n = 0; n < 4; n++) acc[m][n] = {0.f, 0.f, 0.f, 0.f};

  QT_STAGE(0); QT_STAGE(1); QT_STAGE(2);
  WAITVM(6);
  BAR();

  bf16x8 af0[2], bfr0[4], af1[2];
  {
    const bf16* Ab = &smem[0];
    const bf16* Bb = Ab + 4096;
#pragma unroll
    for (int n = 0; n < 4; n++)
      bfr0[n] = *(const bf16x8*)&Bb[(wn + n * 16 + r16) * 32 + sc8];
#pragma unroll
    for (int m = 0; m < 2; m++)
      af0[m] = *(const bf16x8*)&Ab[(wm + m * 16 + r16) * 32 + sc8];
  }

#pragma unroll 4
  for (int tt = 0; tt < NT; ++tt) {
    const bf16* Ab = &smem[(tt & 3) * 12288];

    BAR();  // BAR A
    if (tt + 3 < NT) QT_STAGE(tt + 3);
#pragma unroll
    for (int m = 0; m < 2; m++)
      af1[m] = *(const bf16x8*)&Ab[(wm + (m + 2) * 16 + r16) * 32 + sc8];
    __builtin_amdgcn_s_setprio(1);
#pragma unroll
    for (int m = 0; m < 2; m++)
#pragma unroll
      for (int n = 0; n < 4; n++)
        acc[m][n] = __builtin_amdgcn_mfma_f32_16x16x32_bf16(af0[m], bfr0[n], acc[m][n], 0, 0, 0);
    __builtin_amdgcn_s_setprio(0);

    if (tt <= NT - 4)      { WAITVM(6); }
    else if (tt == NT - 3) { WAITVM(3); }
    else if (tt == NT - 2) { WAITVM(0); }
    BAR();  // BAR B

    __builtin_amdgcn_s_setprio(1);
#pragma unroll
    for (int m = 0; m < 2; m++)
#pragma unroll
      for (int n = 0; n < 4; n++)
        acc[m + 2][n] = __builtin_amdgcn_mfma_f32_16x16x32_bf16(af1[m], bfr0[n], acc[m + 2][n], 0, 0, 0);
    __builtin_amdgcn_s_setprio(0);

    if (tt + 1 < NT) {
      const bf16* Ab2 = &smem[((tt + 1) & 3) * 12288];
      const bf16* Bb2 = Ab2 + 4096;
#pragma unroll
      for (int n = 0; n < 4; n++)
        bfr0[n] = *(const bf16x8*)&Bb2[(wn + n * 16 + r16) * 32 + sc8];
#pragma unroll
      for (int m = 0; m < 2; m++)
        af0[m] = *(const bf16x8*)&Ab2[(wm + m * 16 + r16) * 32 + sc8];
    }
  }

  // epilogue: per-wave 64x64 sub-tile -> QT[b][s][u], bf16
  bf16* Cp = QT + (long)b * S * Cn + (long)m0 * Cn + n0;
#pragma unroll
  for (int m = 0; m < 4; m++)
#pragma unroll
    for (int n = 0; n < 4; n++)
#pragma unroll
      for (int r = 0; r < 4; r++) {
        const int row = wm + m * 16 + quad * 4 + r;
        const int col = wn + n * 16 + r16;
        Cp[(long)row * Cn + col] = __float2bfloat16(acc[m][n][r]);
      }
#undef QT_STAGE
}

// ---- both weight matrices f32 -> bf16, float4-vectorized, one dispatch ----
__global__ __launch_bounds__(256) void k_cvt_w(
    const float* __restrict__ Wqkv, const float* __restrict__ Wout,
    bf16* __restrict__ WqkvB, bf16* __restrict__ WoutB)
{
  const long v = (long)blockIdx.x * 256 + threadIdx.x;  // 1,048,576 vec4 total
  const bool isQ = v < 786432;
  const float4 f = isQ ? ((const float4*)Wqkv)[v] : ((const float4*)Wout)[v - 786432];
  bf16 tmp[4];
  tmp[0] = __float2bfloat16(f.x);
  tmp[1] = __float2bfloat16(f.y);
  tmp[2] = __float2bfloat16(f.z);
  tmp[3] = __float2bfloat16(f.w);
  ushort4 u = *(ushort4*)tmp;
  if (isQ) ((ushort4*)WqkvB)[v] = u;
  else     ((ushort4*)WoutB)[v - 786432] = u;
}

// ---- transpose+convert: f32 (1024 x 2048) -> bf16 (2048 x 1024) per z ----
__global__ __launch_bounds__(256) void k_transpose_cvt(
    const float* __restrict__ in, bf16* __restrict__ out, long inZ, long outZ)
{
  __shared__ bf16 tile[32][33];
  const float* ip = in + (long)blockIdx.z * inZ;
  bf16* op = out + (long)blockIdx.z * outZ;
  const int c0 = blockIdx.x * 32, r0 = blockIdx.y * 32;
  const int tx = threadIdx.x & 31, ty = threadIdx.x >> 5;  // 32 x 8
#pragma unroll
  for (int i = 0; i < 32; i += 8)
    tile[ty + i][tx] = __float2bfloat16(ip[(long)(r0 + ty + i) * 2048 + c0 + tx]);
  __syncthreads();
#pragma unroll
  for (int i = 0; i < 32; i += 8)
    op[(long)(c0 + ty + i) * 1024 + r0 + tx] = tile[tx][ty + i];
}

// ---- MTpart[chunk][z][e][d] = K_h . V_h^T over a 256-wide s-chunk ----
__global__ __launch_bounds__(256) void k_gemm_mt(
    const bf16* __restrict__ KV, float* __restrict__ MTpart)
{
  const int chunk = blockIdx.x;               // 8 chunks of 256 along s
  const int z = blockIdx.y;                   // b*8 + h
  const int b = z >> 3, h = z & 7;
  const bf16* base = KV + (long)b * 2048 * S;
  const bf16* A  = base + (long)(h * Dh) * S + chunk * 256;
  const bf16* Bp = base + (long)(1024 + h * Dh) * S + chunk * 256;
  f32x4 acc[4][4];
  gemm_bt_core(A, S, Bp, S, 8, acc);
  store_f32_tile(acc, MTpart + ((long)chunk * 32 + z) * (Dh * Dh), Dh);
}

// ---- MbT[z][e][d] = bf16(SCALE * sum_chunk MTpart) ----
__global__ __launch_bounds__(256) void k_reduce_mt(
    const float* __restrict__ MTpart, bf16* __restrict__ MbT)
{
  const long i = (long)blockIdx.x * 256 + threadIdx.x;  // 524,288 total
  float s = 0.f;
#pragma unroll
  for (int c = 0; c < 8; c++) s += MTpart[(long)c * 32 * Dh * Dh + i];
  MbT[i] = __float2bfloat16(s * SCALE);
}

// ---- W2[b][o][h*128+e] = sum_d Wout[o][h*128+d] * MbT[b,h][e][d] ----
__global__ __launch_bounds__(256) void k_gemm_w2(
    const bf16* __restrict__ WoutB, const bf16* __restrict__ MbT, bf16* __restrict__ W2)
{
  const int m0 = blockIdx.x * 128;
  const int h = blockIdx.y, b = blockIdx.z;
  const int z = b * 8 + h;
  f32x4 acc[4][4];
  gemm_bt_core(WoutB + (long)m0 * Cn + h * Dh, Cn,
               MbT + (long)z * Dh * Dh, Dh, 4, acc);
  store_bf16_tile(acc, W2 + (long)b * Cn * Cn + (long)m0 * Cn + h * Dh, Cn);
}

extern "C" void kernel_launch(void* const* d_in, const int* in_sizes, int n_in,
                              void* d_out, int out_size, void* d_ws, size_t ws_size,
                              hipStream_t stream)
{
  const float* x    = (const float*)d_in[0];  // (4,1024,2048) f32
  const float* Wqkv = (const float*)d_in[1];  // (3072,1024)   f32
  const float* Wout = (const float*)d_in[2];  // (1024,1024)   f32
  float* out = (float*)d_out;                 // (4,1024,2048) f32

  char* ws = (char*)d_ws;
  bf16*  KV     = (bf16*)ws;                     // 33,554,432 B
  bf16*  xT     = (bf16*)(ws + 33554432);        // 16,777,216 B (live till end)
  float* MTpart = (float*)(ws + 50331648);       // 16,777,216 B (dead after reduce)
  bf16*  QT     = (bf16*)(ws + 50331648);        // 16,777,216 B (aliases MTpart)
  bf16*  WqkvB  = (bf16*)(ws + 67108864);        //  6,291,456 B
  bf16*  WoutB  = (bf16*)(ws + 73400320);        //  2,097,152 B
  bf16*  MbT    = (bf16*)(ws + 75497472);        //  1,048,576 B
  bf16*  W2     = (bf16*)(ws + 76546048);        //  8,388,608 B (end 84,934,656)
  bf16*  WkvB   = WqkvB + (long)Cn * Cn;         // K,V rows of WqkvB

  // weights f32 -> bf16 (one dispatch, float4)
  k_cvt_w<<<dim3(4096), 256, 0, stream>>>(Wqkv, Wout, WqkvB, WoutB);
  // xT[b] = bf16(x[b]^T)
  k_transpose_cvt<<<dim3(64, 32, 4), 256, 0, stream>>>(
      x, xT, (long)1024 * 2048, (long)2048 * 1024);
  // K,V in (o,s) layout, 256^2-tile pipelined GEMM (all batches)
  k_gemm_kv8<<<dim3(256), 512, 0, stream>>>(WkvB, xT, KV);
  // MT partials: K_h . V_h^T over 8 s-chunks (no atomics)
  k_gemm_mt<<<dim3(8, 32), 256, 0, stream>>>(KV, MTpart);
  // MbT = bf16(SCALE * sum of partials)
  k_reduce_mt<<<dim3(2048), 256, 0, stream>>>(MTpart, MbT);
  // W2[b] = Wout . blockdiag(scale*M): folded output weights
  k_gemm_w2<<<dim3(8, 8, 4), 256, 0, stream>>>(WoutB, MbT, W2);
  // QT[b] = (Wq . x[b])^T  (fast-core shape; replaces slow W3 fold)
  k_gemm_qt8<<<dim3(256), 512, 0, stream>>>(xT, WqkvB, QT);
  // out[b] = W2[b] . Q[b]  (f32 output)
  k_gemm_out8<<<dim3(256), 512, 0, stream>>>(W2, QT, out);
}